// Round 4
// baseline (56.776 us; speedup 1.0000x reference)
//
#include <hip/hip_runtime.h>
#include <math.h>

#define HH 512
#define WW 512
#define NPIX (HH*WW)
#define MPTS 100
#define BSZ 4
#define T1B 256   // term1 blocks per batch
#define NCH 64    // term2 chunks per (b, m-group)
#define TM 10     // GT points per term2 block

static constexpr float MAXD = 724.0773439350246f;  // sqrt(512^2 + 512^2)
static constexpr float EPSF = 1e-6f;

// ws float layout (all plain stores, no atomics, no memset needed):
// [0, 1024)        T1P[b][T1B]   term1 weighted-min partial per block
// [1024, 2048)     NP [b][T1B]   n_est partial per block
// [2048, 27648)    S2 [(b*100+m)][NCH]  term2 (wd+eps)^-9 partial sums

__device__ __forceinline__ float wred(float v) {
#pragma unroll
  for (int off = 32; off > 0; off >>= 1) v += __shfl_down(v, off);
  return v;
}

__global__ __launch_bounds__(256) void k_term1(
    const float* __restrict__ pm, const float* __restrict__ gt,
    const float* __restrict__ osz, float* __restrict__ ws) {
  int b = blockIdx.y;
  __shared__ float2 gts[MPTS];
  __shared__ float r1[4], r2[4];
  float nyn = osz[2*b+0] * (1.0f/HH);
  float nxn = osz[2*b+1] * (1.0f/WW);
  for (int i = threadIdx.x; i < MPTS; i += 256)
    gts[i] = make_float2(gt[(b*MPTS+i)*2+0]*nyn, gt[(b*MPTS+i)*2+1]*nxn);
  __syncthreads();
  const float2* pm2 = (const float2*)(pm + (size_t)b*NPIX);
  float t1p = 0.0f, np = 0.0f;
#pragma unroll
  for (int t = 0; t < 2; ++t) {
    int q = blockIdx.x*512 + t*256 + (int)threadIdx.x;  // float2 index
    float2 p2 = pm2[q];
    int n0 = q << 1;
    float py  = (float)(n0 >> 9) * nyn;
    float px0 = (float)(n0 & 511) * nxn;
    float px1 = px0 + nxn;
    float mA = 1e30f, mB = 1e30f;
#pragma unroll 5
    for (int m = 0; m < MPTS; m += 2) {
      float2 ga = gts[m];
      float2 gb = gts[m+1];
      float dya = py - ga.x; float ya2 = dya*dya;
      float dyb = py - gb.x; float yb2 = dyb*dyb;
      float a0 = px0 - ga.y, b0 = px0 - gb.y;
      float a1 = px1 - ga.y, b1 = px1 - gb.y;
      // fminf(chain, fminf(x,y)) -> v_min3_f32
      mA = fminf(mA, fminf(fmaf(a0,a0,ya2), fmaf(b0,b0,yb2)));
      mB = fminf(mB, fminf(fmaf(a1,a1,ya2), fmaf(b1,b1,yb2)));
    }
    t1p += p2.x*__builtin_amdgcn_sqrtf(mA) + p2.y*__builtin_amdgcn_sqrtf(mB);
    np  += p2.x + p2.y;
  }
  t1p = wred(t1p);
  np  = wred(np);
  int w = threadIdx.x >> 6;
  if ((threadIdx.x & 63) == 0) { r1[w] = t1p; r2[w] = np; }
  __syncthreads();
  if (threadIdx.x == 0) {
    ws[b*T1B + blockIdx.x]        = (r1[0]+r1[1])+(r1[2]+r1[3]);
    ws[1024 + b*T1B + blockIdx.x] = (r2[0]+r2[1])+(r2[2]+r2[3]);
  }
}

__global__ __launch_bounds__(256) void k_term2(
    const float* __restrict__ pm, const float* __restrict__ gt,
    const float* __restrict__ osz, float* __restrict__ S2) {
  const int PB = 4;    // float4 groups per thread
  int b  = blockIdx.z;
  int mg = blockIdx.y;
  __shared__ float sacc[4][TM];
  float nyn = osz[2*b+0] * (1.0f/HH);
  float nxn = osz[2*b+1] * (1.0f/WW);
  float gy[TM], gx[TM];
#pragma unroll
  for (int j = 0; j < TM; ++j) {
    int m = mg*TM + j;
    gy[j] = gt[(b*MPTS+m)*2+0]*nyn;
    gx[j] = gt[(b*MPTS+m)*2+1]*nxn;
  }
  float acc[TM];
#pragma unroll
  for (int j = 0; j < TM; ++j) acc[j] = 0.0f;
  const float4* pm4 = (const float4*)(pm + (size_t)b*NPIX);
  int base = blockIdx.x * (256*PB);
#pragma unroll
  for (int t = 0; t < PB; ++t) {
    int q = base + t*256 + (int)threadIdx.x;
    float4 p4 = pm4[q];
    int n0 = q << 2;
    float py  = (float)(n0 >> 9) * nyn;
    float px0 = (float)(n0 & 511) * nxn;
    // c = (1-p)*MAXD + EPS
    float c0 = fmaf(-p4.x, MAXD, MAXD + EPSF);
    float c1 = fmaf(-p4.y, MAXD, MAXD + EPSF);
    float c2 = fmaf(-p4.z, MAXD, MAXD + EPSF);
    float c3 = fmaf(-p4.w, MAXD, MAXD + EPSF);
#pragma unroll
    for (int j = 0; j < TM; j += 2) {
      // --- 8 weighted distances: points j (A) and j+1 (B) x 4 pixels ---
      float dyA  = py - gy[j];
      float yA2  = dyA*dyA;
      float dyB  = py - gy[j+1];
      float yB2  = dyB*dyB;
      float aA0 = px0 - gx[j];
      float aA1 = aA0 + nxn;
      float aA2 = aA1 + nxn;
      float aA3 = aA2 + nxn;
      float aB0 = px0 - gx[j+1];
      float aB1 = aB0 + nxn;
      float aB2 = aB1 + nxn;
      float aB3 = aB2 + nxn;
      float w0 = fmaf(p4.x, __builtin_amdgcn_sqrtf(fmaf(aA0,aA0,yA2)), c0);
      float w1 = fmaf(p4.y, __builtin_amdgcn_sqrtf(fmaf(aA1,aA1,yA2)), c1);
      float w2 = fmaf(p4.z, __builtin_amdgcn_sqrtf(fmaf(aA2,aA2,yA2)), c2);
      float w3 = fmaf(p4.w, __builtin_amdgcn_sqrtf(fmaf(aA3,aA3,yA2)), c3);
      float w4 = fmaf(p4.x, __builtin_amdgcn_sqrtf(fmaf(aB0,aB0,yB2)), c0);
      float w5 = fmaf(p4.y, __builtin_amdgcn_sqrtf(fmaf(aB1,aB1,yB2)), c1);
      float w6 = fmaf(p4.z, __builtin_amdgcn_sqrtf(fmaf(aB2,aB2,yB2)), c2);
      float w7 = fmaf(p4.w, __builtin_amdgcn_sqrtf(fmaf(aB3,aB3,yB2)), c3);
      // --- Montgomery batch inversion: 8 reciprocals, ONE v_rcp ---
      // products <= 724^8 ~ 7.6e22 (no overflow); w >= ~4e-5 (no underflow)
      float q1 = w0*w1, q2 = q1*w2, q3 = q2*w3;
      float q4 = q3*w4, q5 = q4*w5, q6 = q5*w6, q7 = q6*w7;
      float r  = __builtin_amdgcn_rcpf(q7);
      float u7 = r*q6; r *= w7;
      float u6 = r*q5; r *= w6;
      float u5 = r*q4; r *= w5;
      float u4 = r*q3; r *= w4;
      float u3 = r*q2; r *= w3;
      float u2 = r*q1; r *= w2;
      float u1 = r*w0;
      float u0 = r*w1;
      // --- u^9 accumulate ---
      float e0 = u0*u0; e0 *= e0; e0 *= e0;
      float e1 = u1*u1; e1 *= e1; e1 *= e1;
      float e2 = u2*u2; e2 *= e2; e2 *= e2;
      float e3 = u3*u3; e3 *= e3; e3 *= e3;
      float sA = fmaf(e0, u0, acc[j]);
      sA = fmaf(e1, u1, sA);
      sA = fmaf(e2, u2, sA);
      acc[j] = fmaf(e3, u3, sA);
      float e4 = u4*u4; e4 *= e4; e4 *= e4;
      float e5 = u5*u5; e5 *= e5; e5 *= e5;
      float e6 = u6*u6; e6 *= e6; e6 *= e6;
      float e7 = u7*u7; e7 *= e7; e7 *= e7;
      float sB = fmaf(e4, u4, acc[j+1]);
      sB = fmaf(e5, u5, sB);
      sB = fmaf(e6, u6, sB);
      acc[j+1] = fmaf(e7, u7, sB);
    }
  }
  int w = threadIdx.x >> 6;
#pragma unroll
  for (int j = 0; j < TM; ++j) {
    float v = wred(acc[j]);
    if ((threadIdx.x & 63) == 0) sacc[w][j] = v;
  }
  __syncthreads();
  if (threadIdx.x < TM) {
    float s = (sacc[0][threadIdx.x] + sacc[1][threadIdx.x])
            + (sacc[2][threadIdx.x] + sacc[3][threadIdx.x]);
    S2[(b*MPTS + mg*TM + (int)threadIdx.x)*NCH + blockIdx.x] = s;
  }
}

__global__ __launch_bounds__(512) void k_final(
    const float* __restrict__ ws, float* __restrict__ out) {
  __shared__ float smT[512], smA[512], smN[512];
  int i = threadIdx.x;
  // term2: reduce chunks, power mean
  float v = 0.0f;
  if (i < BSZ*MPTS) {
    const float* p = ws + 2048 + i*NCH;
    float s = 0.0f;
#pragma unroll
    for (int c = 0; c < NCH; ++c) s += p[c];
    // (s/N)^(-1/9) = exp2(log2(s/N) * -1/9)
    v = __builtin_amdgcn_exp2f(__builtin_amdgcn_logf(s * (1.0f/(float)NPIX))
                               * (-1.0f/9.0f));
  }
  smT[i] = v;
  __syncthreads();
  for (int s = 256; s > 0; s >>= 1) {
    if (i < s) smT[i] += smT[i+s];
    __syncthreads();
  }
  // term1: per-batch reduce of T1B=256 partials
  int b = i >> 7, j = i & 127;
  smA[i] = ws[b*T1B + j]        + ws[b*T1B + j + 128];
  smN[i] = ws[1024 + b*T1B + j] + ws[1024 + b*T1B + j + 128];
  __syncthreads();
  for (int s = 64; s > 0; s >>= 1) {
    if (j < s) { smA[i] += smA[i+s]; smN[i] += smN[i+s]; }
    __syncthreads();
  }
  if (i == 0) {
    float t1 = 0.0f;
    for (int bb = 0; bb < BSZ; ++bb)
      t1 += smA[bb*128] / (smN[bb*128] + EPSF);
    out[0] = t1 * (1.0f/(float)BSZ) + smT[0] * (1.0f/(float)(BSZ*MPTS));
  }
}

extern "C" void kernel_launch(void* const* d_in, const int* in_sizes, int n_in,
                              void* d_out, int out_size, void* d_ws, size_t ws_size,
                              hipStream_t stream) {
  const float* pm  = (const float*)d_in[0];
  const float* gt  = (const float*)d_in[1];
  const float* osz = (const float*)d_in[2];
  float* out = (float*)d_out;
  float* ws  = (float*)d_ws;

  // term1: 256 blocks/batch x 4 batches = 1024 blocks, 4 px/thread, no atomics
  k_term1<<<dim3(T1B, BSZ), 256, 0, stream>>>(pm, gt, osz, ws);

  // term2: 64 chunks x 10 m-groups x 4 batches = 2560 blocks, no atomics
  k_term2<<<dim3(NCH, MPTS/TM, BSZ), 256, 0, stream>>>(pm, gt, osz, ws + 2048);

  // single-block hierarchical reduce + power-mean + final scalar
  k_final<<<1, 512, 0, stream>>>(ws, out);
}

// Round 5
// 26.780 us; speedup vs baseline: 2.1201x; 2.1201x over previous
//
#include <hip/hip_runtime.h>
#include <math.h>

#define HH 512
#define WW 512
#define NPIX (HH*WW)
#define MPTS 100
#define BSZ 4
#define T1B 256          // term1 blocks per batch
#define BOXW 224         // term2 box width/height (pixels)
#define BOXQ (BOXW/4)    // 56 quads per box row
#define T2CH 7           // term2 chunks (blocks) per (b,m)
#define QPT 7            // quads per thread (7*256*7 = 12544 = BOXW*BOXQ)

static constexpr float MAXD = 724.0773439350246f;  // sqrt(512^2 + 512^2)
static constexpr float EPSF = 1e-6f;

// ws float layout (plain stores only, no atomics, no memset):
// [0, 1024)       T1P[b][T1B]
// [1024, 2048)    NP [b][T1B]
// [2048, 4848)    S2 [(b*100+m)][T2CH]

__device__ __forceinline__ float wred(float v) {
#pragma unroll
  for (int off = 32; off > 0; off >>= 1) v += __shfl_down(v, off);
  return v;
}

__global__ __launch_bounds__(256) void k_term1(
    const float* __restrict__ pm, const float* __restrict__ gt,
    const float* __restrict__ osz, float* __restrict__ ws) {
  int b = blockIdx.y;
  __shared__ float2 gts[MPTS];
  __shared__ float r1[4], r2[4];
  float nyn = osz[2*b+0] * (1.0f/HH);
  float nxn = osz[2*b+1] * (1.0f/WW);
  for (int i = threadIdx.x; i < MPTS; i += 256)
    gts[i] = make_float2(gt[(b*MPTS+i)*2+0]*nyn, gt[(b*MPTS+i)*2+1]*nxn);
  __syncthreads();
  const float2* pm2 = (const float2*)(pm + (size_t)b*NPIX);
  float t1p = 0.0f, np = 0.0f;
#pragma unroll
  for (int t = 0; t < 2; ++t) {
    int q = blockIdx.x*512 + t*256 + (int)threadIdx.x;  // float2 index
    float2 p2 = pm2[q];
    int n0 = q << 1;
    float py  = (float)(n0 >> 9) * nyn;
    float px0 = (float)(n0 & 511) * nxn;
    float px1 = px0 + nxn;
    float mA = 1e30f, mB = 1e30f;
#pragma unroll 5
    for (int m = 0; m < MPTS; m += 2) {
      float2 ga = gts[m];
      float2 gb = gts[m+1];
      float dya = py - ga.x; float ya2 = dya*dya;
      float dyb = py - gb.x; float yb2 = dyb*dyb;
      float a0 = px0 - ga.y, b0 = px0 - gb.y;
      float a1 = px1 - ga.y, b1 = px1 - gb.y;
      // fminf(chain, fminf(x,y)) -> v_min3_f32
      mA = fminf(mA, fminf(fmaf(a0,a0,ya2), fmaf(b0,b0,yb2)));
      mB = fminf(mB, fminf(fmaf(a1,a1,ya2), fmaf(b1,b1,yb2)));
    }
    t1p += p2.x*__builtin_amdgcn_sqrtf(mA) + p2.y*__builtin_amdgcn_sqrtf(mB);
    np  += p2.x + p2.y;
  }
  t1p = wred(t1p);
  np  = wred(np);
  int w = threadIdx.x >> 6;
  if ((threadIdx.x & 63) == 0) { r1[w] = t1p; r2[w] = np; }
  __syncthreads();
  if (threadIdx.x == 0) {
    ws[b*T1B + blockIdx.x]        = (r1[0]+r1[1])+(r1[2]+r1[3]);
    ws[1024 + b*T1B + blockIdx.x] = (r2[0]+r2[1])+(r2[2]+r2[3]);
  }
}

// term2 with distance culling: wd >= d, tail beyond D=108 px is < 1e-4
// relative for any realistic minn -> sum only a 224x224 box per GT point.
__global__ __launch_bounds__(256) void k_term2(
    const float* __restrict__ pm, const float* __restrict__ gt,
    const float* __restrict__ osz, float* __restrict__ S2) {
  int b = blockIdx.z, m = blockIdx.y;
  __shared__ float sacc[4];
  float nyn = osz[2*b+0] * (1.0f/HH);
  float nxn = osz[2*b+1] * (1.0f/WW);
  float gr = gt[(b*MPTS+m)*2+0];   // pixel coords
  float gc = gt[(b*MPTS+m)*2+1];
  int rc = (int)gr, cc = (int)gc;
  int r0 = min(max(rc - 112, 0), HH - BOXW);
  int c0 = min(max(cc - 112, 0), WW - BOXW) & ~3;  // float4-aligned
  float gy = gr * nyn, gx = gc * nxn;
  const float4* pm4 = (const float4*)(pm + (size_t)b*NPIX);
  int cq0 = c0 >> 2;
  int baseq = blockIdx.x*(256*QPT) + (int)threadIdx.x;
  float acc = 0.0f;
#pragma unroll
  for (int k = 0; k < QPT; ++k) {
    int idx = baseq + k*256;          // 0..12543
    int row = idx / BOXQ;             // magic-mul div
    int cq  = idx - row*BOXQ;
    int ra  = r0 + row;
    int ca  = c0 + (cq << 2);
    float4 p4 = pm4[(ra << 7) + cq0 + cq];
    float py  = (float)ra * nyn;
    float px0 = (float)ca * nxn;
    float dy  = py - gy;
    float dy2 = dy*dy;
    float dx0 = px0 - gx;
    float dx1 = dx0 + nxn;
    float dx2 = dx1 + nxn;
    float dx3 = dx2 + nxn;
    float cf0 = fmaf(-p4.x, MAXD, MAXD + EPSF);
    float cf1 = fmaf(-p4.y, MAXD, MAXD + EPSF);
    float cf2 = fmaf(-p4.z, MAXD, MAXD + EPSF);
    float cf3 = fmaf(-p4.w, MAXD, MAXD + EPSF);
    float w0 = fmaf(p4.x, __builtin_amdgcn_sqrtf(fmaf(dx0,dx0,dy2)), cf0);
    float w1 = fmaf(p4.y, __builtin_amdgcn_sqrtf(fmaf(dx1,dx1,dy2)), cf1);
    float w2 = fmaf(p4.z, __builtin_amdgcn_sqrtf(fmaf(dx2,dx2,dy2)), cf2);
    float w3 = fmaf(p4.w, __builtin_amdgcn_sqrtf(fmaf(dx3,dx3,dy2)), cf3);
    float i0 = __builtin_amdgcn_rcpf(w0);
    float i1 = __builtin_amdgcn_rcpf(w1);
    float i2 = __builtin_amdgcn_rcpf(w2);
    float i3 = __builtin_amdgcn_rcpf(w3);
    float e0 = i0*i0; e0 *= e0; e0 *= e0;   // i^8
    float e1 = i1*i1; e1 *= e1; e1 *= e1;
    float e2 = i2*i2; e2 *= e2; e2 *= e2;
    float e3 = i3*i3; e3 *= e3; e3 *= e3;
    float s = fmaf(e0, i0, acc);
    s = fmaf(e1, i1, s);
    s = fmaf(e2, i2, s);
    acc = fmaf(e3, i3, s);
  }
  acc = wred(acc);
  int w = threadIdx.x >> 6;
  if ((threadIdx.x & 63) == 0) sacc[w] = acc;
  __syncthreads();
  if (threadIdx.x == 0)
    S2[(b*MPTS + m)*T2CH + blockIdx.x] =
        (sacc[0]+sacc[1]) + (sacc[2]+sacc[3]);
}

__global__ __launch_bounds__(512) void k_final(
    const float* __restrict__ ws, float* __restrict__ out) {
  __shared__ float smT[512], smA[512], smN[512];
  int i = threadIdx.x;
  // term2: reduce chunks, power mean
  float v = 0.0f;
  if (i < BSZ*MPTS) {
    const float* p = ws + 2048 + i*T2CH;
    float s = 0.0f;
#pragma unroll
    for (int c = 0; c < T2CH; ++c) s += p[c];
    // (s/N)^(-1/9) = exp2(log2(s/N) * -1/9)
    v = __builtin_amdgcn_exp2f(__builtin_amdgcn_logf(s * (1.0f/(float)NPIX))
                               * (-1.0f/9.0f));
  }
  smT[i] = v;
  __syncthreads();
  for (int s = 256; s > 0; s >>= 1) {
    if (i < s) smT[i] += smT[i+s];
    __syncthreads();
  }
  // term1: per-batch reduce of T1B=256 partials
  int b = i >> 7, j = i & 127;
  smA[i] = ws[b*T1B + j]        + ws[b*T1B + j + 128];
  smN[i] = ws[1024 + b*T1B + j] + ws[1024 + b*T1B + j + 128];
  __syncthreads();
  for (int s = 64; s > 0; s >>= 1) {
    if (j < s) { smA[i] += smA[i+s]; smN[i] += smN[i+s]; }
    __syncthreads();
  }
  if (i == 0) {
    float t1 = 0.0f;
    for (int bb = 0; bb < BSZ; ++bb)
      t1 += smA[bb*128] / (smN[bb*128] + EPSF);
    out[0] = t1 * (1.0f/(float)BSZ) + smT[0] * (1.0f/(float)(BSZ*MPTS));
  }
}

extern "C" void kernel_launch(void* const* d_in, const int* in_sizes, int n_in,
                              void* d_out, int out_size, void* d_ws, size_t ws_size,
                              hipStream_t stream) {
  const float* pm  = (const float*)d_in[0];
  const float* gt  = (const float*)d_in[1];
  const float* osz = (const float*)d_in[2];
  float* out = (float*)d_out;
  float* ws  = (float*)d_ws;

  // term1: 256 blocks/batch x 4 batches, 4 px/thread, no atomics
  k_term1<<<dim3(T1B, BSZ), 256, 0, stream>>>(pm, gt, osz, ws);

  // term2: 7 chunks x 100 m x 4 batches = 2800 blocks, 224x224 box per (b,m)
  k_term2<<<dim3(T2CH, MPTS, BSZ), 256, 0, stream>>>(pm, gt, osz, ws + 2048);

  // single-block hierarchical reduce + power-mean + final scalar
  k_final<<<1, 512, 0, stream>>>(ws, out);
}

// Round 6
// 22.988 us; speedup vs baseline: 2.4698x; 1.1649x over previous
//
#include <hip/hip_runtime.h>
#include <math.h>

#define HH 512
#define WW 512
#define NPIX (HH*WW)
#define MPTS 100
#define BSZ 4
#define T1B 256          // term1 blocks per batch
#define BOXW 160         // term2 box width/height (pixels)
#define BOXQ (BOXW/4)    // 40 quads per box row
#define T2CH 5           // term2 chunks (blocks) per (b,m)
#define QPT 5            // quads per thread (5*256*5 = 6400 = BOXW*BOXQ)

static constexpr float MAXD = 724.0773439350246f;  // sqrt(512^2 + 512^2)
static constexpr float EPSF = 1e-6f;

// ws float layout (plain stores only, no atomics, no memset):
// [0, 1024)       T1P[b][T1B]
// [1024, 2048)    NP [b][T1B]
// [2048, 4048)    S2 [(b*100+m)][T2CH]

__device__ __forceinline__ float wred(float v) {
#pragma unroll
  for (int off = 32; off > 0; off >>= 1) v += __shfl_down(v, off);
  return v;
}

__global__ __launch_bounds__(256) void k_term1(
    const float* __restrict__ pm, const float* __restrict__ gt,
    const float* __restrict__ osz, float* __restrict__ ws) {
  int b = blockIdx.y;
  __shared__ float2 gts[MPTS];
  __shared__ float r1[4], r2[4];
  float nyn = osz[2*b+0] * (1.0f/HH);
  float nxn = osz[2*b+1] * (1.0f/WW);
  for (int i = threadIdx.x; i < MPTS; i += 256)
    gts[i] = make_float2(gt[(b*MPTS+i)*2+0]*nyn, gt[(b*MPTS+i)*2+1]*nxn);
  __syncthreads();
  const float2* pm2 = (const float2*)(pm + (size_t)b*NPIX);
  float t1p = 0.0f, np = 0.0f;
#pragma unroll
  for (int t = 0; t < 2; ++t) {
    int q = blockIdx.x*512 + t*256 + (int)threadIdx.x;  // float2 index
    float2 p2 = pm2[q];
    int n0 = q << 1;
    float py  = (float)(n0 >> 9) * nyn;
    float px0 = (float)(n0 & 511) * nxn;
    float px1 = px0 + nxn;
    float mA = 1e30f, mB = 1e30f;
#pragma unroll 5
    for (int m = 0; m < MPTS; m += 2) {
      float2 ga = gts[m];
      float2 gb = gts[m+1];
      float dya = py - ga.x; float ya2 = dya*dya;
      float dyb = py - gb.x; float yb2 = dyb*dyb;
      float a0 = px0 - ga.y, b0 = px0 - gb.y;
      float a1 = px1 - ga.y, b1 = px1 - gb.y;
      // fminf(chain, fminf(x,y)) -> v_min3_f32
      mA = fminf(mA, fminf(fmaf(a0,a0,ya2), fmaf(b0,b0,yb2)));
      mB = fminf(mB, fminf(fmaf(a1,a1,ya2), fmaf(b1,b1,yb2)));
    }
    t1p += p2.x*__builtin_amdgcn_sqrtf(mA) + p2.y*__builtin_amdgcn_sqrtf(mB);
    np  += p2.x + p2.y;
  }
  t1p = wred(t1p);
  np  = wred(np);
  int w = threadIdx.x >> 6;
  if ((threadIdx.x & 63) == 0) { r1[w] = t1p; r2[w] = np; }
  __syncthreads();
  if (threadIdx.x == 0) {
    ws[b*T1B + blockIdx.x]        = (r1[0]+r1[1])+(r1[2]+r1[3]);
    ws[1024 + b*T1B + blockIdx.x] = (r2[0]+r2[1])+(r2[2]+r2[3]);
  }
}

// term2 with distance culling: wd >= d, so pixels beyond the guaranteed
// coverage radius (77 px) contribute < 6e-14 absolute to S_m -- negligible
// even for pathological minn. 160x160 box per GT point.
__global__ __launch_bounds__(256) void k_term2(
    const float* __restrict__ pm, const float* __restrict__ gt,
    const float* __restrict__ osz, float* __restrict__ S2) {
  int b = blockIdx.z, m = blockIdx.y;
  __shared__ float sacc[4];
  float nyn = osz[2*b+0] * (1.0f/HH);
  float nxn = osz[2*b+1] * (1.0f/WW);
  float gr = gt[(b*MPTS+m)*2+0];   // pixel coords
  float gc = gt[(b*MPTS+m)*2+1];
  int rc = (int)gr, cc = (int)gc;
  int r0 = min(max(rc - BOXW/2, 0), HH - BOXW);
  int c0 = min(max(cc - BOXW/2, 0), WW - BOXW) & ~3;  // float4-aligned
  float gy = gr * nyn, gx = gc * nxn;
  const float4* pm4 = (const float4*)(pm + (size_t)b*NPIX);
  int cq0 = c0 >> 2;
  int baseq = blockIdx.x*(256*QPT) + (int)threadIdx.x;
  float acc = 0.0f;
#pragma unroll
  for (int k = 0; k < QPT; ++k) {
    int idx = baseq + k*256;          // 0..6399
    int row = idx / BOXQ;             // magic-mul div
    int cq  = idx - row*BOXQ;
    int ra  = r0 + row;
    int ca  = c0 + (cq << 2);
    float4 p4 = pm4[(ra << 7) + cq0 + cq];
    float py  = (float)ra * nyn;
    float px0 = (float)ca * nxn;
    float dy  = py - gy;
    float dy2 = dy*dy;
    float dx0 = px0 - gx;
    float dx1 = dx0 + nxn;
    float dx2 = dx1 + nxn;
    float dx3 = dx2 + nxn;
    float cf0 = fmaf(-p4.x, MAXD, MAXD + EPSF);
    float cf1 = fmaf(-p4.y, MAXD, MAXD + EPSF);
    float cf2 = fmaf(-p4.z, MAXD, MAXD + EPSF);
    float cf3 = fmaf(-p4.w, MAXD, MAXD + EPSF);
    float w0 = fmaf(p4.x, __builtin_amdgcn_sqrtf(fmaf(dx0,dx0,dy2)), cf0);
    float w1 = fmaf(p4.y, __builtin_amdgcn_sqrtf(fmaf(dx1,dx1,dy2)), cf1);
    float w2 = fmaf(p4.z, __builtin_amdgcn_sqrtf(fmaf(dx2,dx2,dy2)), cf2);
    float w3 = fmaf(p4.w, __builtin_amdgcn_sqrtf(fmaf(dx3,dx3,dy2)), cf3);
    float i0 = __builtin_amdgcn_rcpf(w0);
    float i1 = __builtin_amdgcn_rcpf(w1);
    float i2 = __builtin_amdgcn_rcpf(w2);
    float i3 = __builtin_amdgcn_rcpf(w3);
    float e0 = i0*i0; e0 *= e0; e0 *= e0;   // i^8
    float e1 = i1*i1; e1 *= e1; e1 *= e1;
    float e2 = i2*i2; e2 *= e2; e2 *= e2;
    float e3 = i3*i3; e3 *= e3; e3 *= e3;
    float s = fmaf(e0, i0, acc);
    s = fmaf(e1, i1, s);
    s = fmaf(e2, i2, s);
    acc = fmaf(e3, i3, s);
  }
  acc = wred(acc);
  int w = threadIdx.x >> 6;
  if ((threadIdx.x & 63) == 0) sacc[w] = acc;
  __syncthreads();
  if (threadIdx.x == 0)
    S2[(b*MPTS + m)*T2CH + blockIdx.x] =
        (sacc[0]+sacc[1]) + (sacc[2]+sacc[3]);
}

__global__ __launch_bounds__(512) void k_final(
    const float* __restrict__ ws, float* __restrict__ out) {
  __shared__ float smT[512], smA[512], smN[512];
  int i = threadIdx.x;
  // term2: reduce chunks, power mean
  float v = 0.0f;
  if (i < BSZ*MPTS) {
    const float* p = ws + 2048 + i*T2CH;
    float s = 0.0f;
#pragma unroll
    for (int c = 0; c < T2CH; ++c) s += p[c];
    // (s/N)^(-1/9) = exp2(log2(s/N) * -1/9)
    v = __builtin_amdgcn_exp2f(__builtin_amdgcn_logf(s * (1.0f/(float)NPIX))
                               * (-1.0f/9.0f));
  }
  smT[i] = v;
  __syncthreads();
  for (int s = 256; s > 0; s >>= 1) {
    if (i < s) smT[i] += smT[i+s];
    __syncthreads();
  }
  // term1: per-batch reduce of T1B=256 partials
  int b = i >> 7, j = i & 127;
  smA[i] = ws[b*T1B + j]        + ws[b*T1B + j + 128];
  smN[i] = ws[1024 + b*T1B + j] + ws[1024 + b*T1B + j + 128];
  __syncthreads();
  for (int s = 64; s > 0; s >>= 1) {
    if (j < s) { smA[i] += smA[i+s]; smN[i] += smN[i+s]; }
    __syncthreads();
  }
  if (i == 0) {
    float t1 = 0.0f;
    for (int bb = 0; bb < BSZ; ++bb)
      t1 += smA[bb*128] / (smN[bb*128] + EPSF);
    out[0] = t1 * (1.0f/(float)BSZ) + smT[0] * (1.0f/(float)(BSZ*MPTS));
  }
}

extern "C" void kernel_launch(void* const* d_in, const int* in_sizes, int n_in,
                              void* d_out, int out_size, void* d_ws, size_t ws_size,
                              hipStream_t stream) {
  const float* pm  = (const float*)d_in[0];
  const float* gt  = (const float*)d_in[1];
  const float* osz = (const float*)d_in[2];
  float* out = (float*)d_out;
  float* ws  = (float*)d_ws;

  // term1: 256 blocks/batch x 4 batches, 4 px/thread, no atomics
  k_term1<<<dim3(T1B, BSZ), 256, 0, stream>>>(pm, gt, osz, ws);

  // term2: 5 chunks x 100 m x 4 batches = 2000 blocks, 160x160 box per (b,m)
  k_term2<<<dim3(T2CH, MPTS, BSZ), 256, 0, stream>>>(pm, gt, osz, ws + 2048);

  // single-block hierarchical reduce + power-mean + final scalar
  k_final<<<1, 512, 0, stream>>>(ws, out);
}

// Round 7
// 19.882 us; speedup vs baseline: 2.8556x; 1.1562x over previous
//
#include <hip/hip_runtime.h>
#include <math.h>

#define HH 512
#define WW 512
#define NPIX (HH*WW)
#define MPTS 100
#define BSZ 4
#define T1BB 128         // term1 blocks per batch (512 total, 8 px/thread)
#define T1G  4           // float2 groups per term1 thread
#define BOXW 160         // term2 box width/height (pixels)
#define BOXQ (BOXW/4)    // 40 quads per box row
#define T2CH 5           // term2 chunks per (b,m)
#define QPT 5            // quads per term2 thread (5*256*5 = 6400)
#define NT1 (T1BB*BSZ)   // 512 term1 blocks
#define NT2 (T2CH*MPTS*BSZ) // 2000 term2 blocks

static constexpr float MAXD = 724.0773439350246f;  // sqrt(512^2 + 512^2)
static constexpr float EPSF = 1e-6f;

// ws float layout (plain stores only, no atomics, no memset):
// [0, 512)       T1P[b][T1BB]
// [512, 1024)    NP [b][T1BB]
// [1024, 3024)   S2 [(b*100+m)][T2CH]

__device__ __forceinline__ float wred(float v) {
#pragma unroll
  for (int off = 32; off > 0; off >>= 1) v += __shfl_down(v, off);
  return v;
}

// Fused: blocks [0, NT1) do term1, blocks [NT1, NT1+NT2) do term2.
__global__ __launch_bounds__(256) void k_main(
    const float* __restrict__ pm, const float* __restrict__ gt,
    const float* __restrict__ osz, float* __restrict__ ws) {
  int bid = blockIdx.x;
  __shared__ float2 gts[MPTS];
  __shared__ float r1[4], r2[4];

  if (bid < NT1) {
    // ---------------- term1 ----------------
    int b   = bid >> 7;          // / T1BB
    int blk = bid & (T1BB-1);
    float nyn = osz[2*b+0] * (1.0f/HH);
    float nxn = osz[2*b+1] * (1.0f/WW);
    for (int i = threadIdx.x; i < MPTS; i += 256)
      gts[i] = make_float2(gt[(b*MPTS+i)*2+0]*nyn, gt[(b*MPTS+i)*2+1]*nxn);
    __syncthreads();
    const float2* pm2 = (const float2*)(pm + (size_t)b*NPIX);
    float t1p = 0.0f, np = 0.0f;
#pragma unroll
    for (int t = 0; t < T1G; ++t) {
      int q = blk*(256*T1G) + t*256 + (int)threadIdx.x;  // float2 index
      float2 p2 = pm2[q];
      int n0 = q << 1;
      float py  = (float)(n0 >> 9) * nyn;
      float px0 = (float)(n0 & 511) * nxn;
      float px1 = px0 + nxn;
      float mA = 1e30f, mB = 1e30f;
#pragma unroll 5
      for (int m = 0; m < MPTS; m += 2) {
        float2 ga = gts[m];
        float2 gb = gts[m+1];
        float dya = py - ga.x; float ya2 = dya*dya;
        float dyb = py - gb.x; float yb2 = dyb*dyb;
        float a0 = px0 - ga.y, b0 = px0 - gb.y;
        float a1 = px1 - ga.y, b1 = px1 - gb.y;
        // fminf(chain, fminf(x,y)) -> v_min3_f32
        mA = fminf(mA, fminf(fmaf(a0,a0,ya2), fmaf(b0,b0,yb2)));
        mB = fminf(mB, fminf(fmaf(a1,a1,ya2), fmaf(b1,b1,yb2)));
      }
      t1p += p2.x*__builtin_amdgcn_sqrtf(mA) + p2.y*__builtin_amdgcn_sqrtf(mB);
      np  += p2.x + p2.y;
    }
    t1p = wred(t1p);
    np  = wred(np);
    int w = threadIdx.x >> 6;
    if ((threadIdx.x & 63) == 0) { r1[w] = t1p; r2[w] = np; }
    __syncthreads();
    if (threadIdx.x == 0) {
      ws[bid]       = (r1[0]+r1[1])+(r1[2]+r1[3]);
      ws[512 + bid] = (r2[0]+r2[1])+(r2[2]+r2[3]);
    }
  } else {
    // ---------------- term2 (distance-culled 160x160 box) ----------------
    // wd >= d: pixels beyond the guaranteed coverage radius (77 px)
    // contribute < 6e-14 absolute to S_m -- negligible.
    int bid2 = bid - NT1;
    int b    = bid2 / (T2CH*MPTS);
    int rem  = bid2 - b*(T2CH*MPTS);
    int m    = rem / T2CH;
    int ch   = rem - m*T2CH;
    float nyn = osz[2*b+0] * (1.0f/HH);
    float nxn = osz[2*b+1] * (1.0f/WW);
    float gr = gt[(b*MPTS+m)*2+0];   // pixel coords
    float gc = gt[(b*MPTS+m)*2+1];
    int rc = (int)gr, cc = (int)gc;
    int r0 = min(max(rc - BOXW/2, 0), HH - BOXW);
    int c0 = min(max(cc - BOXW/2, 0), WW - BOXW) & ~3;  // float4-aligned
    float gy = gr * nyn, gx = gc * nxn;
    const float4* pm4 = (const float4*)(pm + (size_t)b*NPIX);
    int cq0 = c0 >> 2;
    int baseq = ch*(256*QPT) + (int)threadIdx.x;
    float acc = 0.0f;
#pragma unroll
    for (int k = 0; k < QPT; ++k) {
      int idx = baseq + k*256;          // 0..6399
      int row = idx / BOXQ;             // magic-mul div
      int cq  = idx - row*BOXQ;
      int ra  = r0 + row;
      int ca  = c0 + (cq << 2);
      float4 p4 = pm4[(ra << 7) + cq0 + cq];
      float py  = (float)ra * nyn;
      float px0 = (float)ca * nxn;
      float dy  = py - gy;
      float dy2 = dy*dy;
      float dx0 = px0 - gx;
      float dx1 = dx0 + nxn;
      float dx2 = dx1 + nxn;
      float dx3 = dx2 + nxn;
      float cf0 = fmaf(-p4.x, MAXD, MAXD + EPSF);
      float cf1 = fmaf(-p4.y, MAXD, MAXD + EPSF);
      float cf2 = fmaf(-p4.z, MAXD, MAXD + EPSF);
      float cf3 = fmaf(-p4.w, MAXD, MAXD + EPSF);
      float w0 = fmaf(p4.x, __builtin_amdgcn_sqrtf(fmaf(dx0,dx0,dy2)), cf0);
      float w1 = fmaf(p4.y, __builtin_amdgcn_sqrtf(fmaf(dx1,dx1,dy2)), cf1);
      float w2 = fmaf(p4.z, __builtin_amdgcn_sqrtf(fmaf(dx2,dx2,dy2)), cf2);
      float w3 = fmaf(p4.w, __builtin_amdgcn_sqrtf(fmaf(dx3,dx3,dy2)), cf3);
      float i0 = __builtin_amdgcn_rcpf(w0);
      float i1 = __builtin_amdgcn_rcpf(w1);
      float i2 = __builtin_amdgcn_rcpf(w2);
      float i3 = __builtin_amdgcn_rcpf(w3);
      float e0 = i0*i0; e0 *= e0; e0 *= e0;   // i^8
      float e1 = i1*i1; e1 *= e1; e1 *= e1;
      float e2 = i2*i2; e2 *= e2; e2 *= e2;
      float e3 = i3*i3; e3 *= e3; e3 *= e3;
      float s = fmaf(e0, i0, acc);
      s = fmaf(e1, i1, s);
      s = fmaf(e2, i2, s);
      acc = fmaf(e3, i3, s);
    }
    acc = wred(acc);
    int w = threadIdx.x >> 6;
    if ((threadIdx.x & 63) == 0) r1[w] = acc;
    __syncthreads();
    if (threadIdx.x == 0)
      ws[1024 + (b*MPTS + m)*T2CH + ch] = (r1[0]+r1[1])+(r1[2]+r1[3]);
  }
}

__global__ __launch_bounds__(512) void k_final(
    const float* __restrict__ ws, float* __restrict__ out) {
  __shared__ float lds2[8], ldsA[8], ldsN[8];
  int i = threadIdx.x;
  int w = i >> 6;
  // term2: 400 lanes each reduce T2CH chunks + power-mean
  float v = 0.0f;
  if (i < BSZ*MPTS) {
    const float* p = ws + 1024 + i*T2CH;
    float s = ((p[0]+p[1]) + (p[2]+p[3])) + p[4];
    // (s/N)^(-1/9) = exp2(log2(s/N) * -1/9)
    v = __builtin_amdgcn_exp2f(__builtin_amdgcn_logf(s * (1.0f/(float)NPIX))
                               * (-1.0f/9.0f));
  }
  v = wred(v);
  // term1: 512 lanes, wave w covers batch w>>1 (128 partials = 2 waves/batch)
  float a = ws[i];
  float n = ws[512 + i];
  a = wred(a);
  n = wred(n);
  if ((i & 63) == 0) { lds2[w] = v; ldsA[w] = a; ldsN[w] = n; }
  __syncthreads();
  if (i == 0) {
    float t2 = 0.0f;
#pragma unroll
    for (int k = 0; k < 8; ++k) t2 += lds2[k];
    float t1 = 0.0f;
#pragma unroll
    for (int b = 0; b < BSZ; ++b)
      t1 += (ldsA[2*b]+ldsA[2*b+1]) / (ldsN[2*b]+ldsN[2*b+1] + EPSF);
    out[0] = t1 * (1.0f/(float)BSZ) + t2 * (1.0f/(float)(BSZ*MPTS));
  }
}

extern "C" void kernel_launch(void* const* d_in, const int* in_sizes, int n_in,
                              void* d_out, int out_size, void* d_ws, size_t ws_size,
                              hipStream_t stream) {
  const float* pm  = (const float*)d_in[0];
  const float* gt  = (const float*)d_in[1];
  const float* osz = (const float*)d_in[2];
  float* out = (float*)d_out;
  float* ws  = (float*)d_ws;

  // fused term1 (512 blocks) + term2 (2000 blocks), no atomics
  k_main<<<NT1 + NT2, 256, 0, stream>>>(pm, gt, osz, ws);

  // single-block shuffle-reduce + power-mean + final scalar
  k_final<<<1, 512, 0, stream>>>(ws, out);
}